// Round 13
// baseline (244.610 us; speedup 1.0000x reference)
//
#include <hip/hip_runtime.h>
#include <hip/hip_bf16.h>

// Fused LN -> QKV projection (bf16 MFMA 32x32x16 fragments, 256^2, 4-phase
// schedule, single counted vmcnt per K-tile, 2D-clustered XCD mapping),
// RoPE fused into the GEMM epilogue.
// x:(2,4096,2048) f32; wq/wk/wv:(2048,2048) f32 row-major [e][d]; out: q,k,v
// each (2,16,4096,128) f32 concatenated.

typedef float f32x4  __attribute__((ext_vector_type(4)));
typedef float f32x16 __attribute__((ext_vector_type(16)));
typedef __bf16 bf16x8 __attribute__((ext_vector_type(8)));
typedef __bf16 bf16x4 __attribute__((ext_vector_type(4)));

#define DM    2048
#define NSEQ  4096
#define NH    16
#define HD    128
#define NROWS 8192
#define MAT_ELEMS (2ull*NH*NSEQ*HD)

// ---------- async global->LDS (16B/lane, wave-uniform LDS base) --------------
typedef __attribute__((address_space(1))) const void GV;
typedef __attribute__((address_space(3))) void LV;
__device__ __forceinline__ void gload_lds16(const void* g, void* l) {
    __builtin_amdgcn_global_load_lds((GV*)g, (LV*)l, 16, 0, 0);
}

// ------------- LayerNorm + weight f32->bf16 cast, single launch --------------
__global__ __launch_bounds__(256)
void lncvt_kernel(const float* __restrict__ x, const float* __restrict__ g,
                  const float* __restrict__ be,
                  const float* __restrict__ wq, const float* __restrict__ wk,
                  const float* __restrict__ wv,
                  __bf16* __restrict__ xnb, __bf16* __restrict__ wb) {
    int bid = blockIdx.x;
    int tid = threadIdx.x;
    if (bid < NROWS) {
        int row = bid;
        const float4* xr = (const float4*)(x + (size_t)row * DM);
        float4 v0 = xr[tid];
        float4 v1 = xr[tid + 256];
        float s  = v0.x + v0.y + v0.z + v0.w + v1.x + v1.y + v1.z + v1.w;
        float ss = v0.x*v0.x + v0.y*v0.y + v0.z*v0.z + v0.w*v0.w
                 + v1.x*v1.x + v1.y*v1.y + v1.z*v1.z + v1.w*v1.w;
#pragma unroll
        for (int o = 32; o > 0; o >>= 1) {
            s  += __shfl_down(s, o);
            ss += __shfl_down(ss, o);
        }
        __shared__ float red[10];
        int wave = tid >> 6, lane = tid & 63;
        if (lane == 0) { red[wave] = s; red[4 + wave] = ss; }
        __syncthreads();
        if (tid == 0) {
            float S  = red[0] + red[1] + red[2] + red[3];
            float SS = red[4] + red[5] + red[6] + red[7];
            float mu  = S * (1.0f / DM);
            float var = SS * (1.0f / DM) - mu * mu;
            red[8] = mu;
            red[9] = rsqrtf(var + 1e-5f);
        }
        __syncthreads();
        float mu = red[8], rs = red[9];

        const float4* gp = (const float4*)g;
        const float4* bp = (const float4*)be;
        bf16x4* orow = (bf16x4*)(xnb + (size_t)row * DM);
        {
            float4 g0 = gp[tid], b0 = bp[tid];
            bf16x4 o;
            o[0] = (__bf16)((v0.x - mu) * rs * g0.x + b0.x);
            o[1] = (__bf16)((v0.y - mu) * rs * g0.y + b0.y);
            o[2] = (__bf16)((v0.z - mu) * rs * g0.z + b0.z);
            o[3] = (__bf16)((v0.w - mu) * rs * g0.w + b0.w);
            orow[tid] = o;
        }
        {
            float4 g1 = gp[tid + 256], b1 = bp[tid + 256];
            bf16x4 o;
            o[0] = (__bf16)((v1.x - mu) * rs * g1.x + b1.x);
            o[1] = (__bf16)((v1.y - mu) * rs * g1.y + b1.y);
            o[2] = (__bf16)((v1.z - mu) * rs * g1.z + b1.z);
            o[3] = (__bf16)((v1.w - mu) * rs * g1.w + b1.w);
            orow[tid + 256] = o;
        }
    } else {
        int cb = bid - NROWS;                   // 0..6143
        const float* a = (cb < 2048) ? wq : (cb < 4096) ? wk : wv;
        size_t base = ((size_t)(cb & 2047) * 256 + tid) * 8;
        float4 v0 = *(const float4*)(a + base);
        float4 v1 = *(const float4*)(a + base + 4);
        bf16x8 r;
        r[0] = (__bf16)v0.x; r[1] = (__bf16)v0.y; r[2] = (__bf16)v0.z; r[3] = (__bf16)v0.w;
        r[4] = (__bf16)v1.x; r[5] = (__bf16)v1.y; r[6] = (__bf16)v1.z; r[7] = (__bf16)v1.w;
        *(bf16x8*)(wb + (size_t)(cb >> 11) * 4194304 + base) = r;
    }
}

// ==============  256x256 4-phase QKV GEMM, 32x32x16 fragments  ===============
// Tile 256x256, BK=64, 8 waves (2Mx4N), per-wave 128x64 out = 4 m-frags x
// 2 n-frags of 32x32, K in 4 slices of 16.  LDS 128KiB dbuf, XOR-swizzle,
// staging/waits identical to R12 (proven).
// Units: U0=A rows{0-63,128-191} (= frags mi0,1), U1=A{64-127,192-255}
// (= mi2,3); U2=B{0-63,128-191} (= ni0), U3 (= ni1).
// Phases: ph0 read {A mi0,1 all ks; B ni0} + stage U1(kt+1)->Q; MFMA (mi0,1 x ni0).
//         ph1 read {B ni1} + stage U0(kt+2)->P;                 MFMA (mi0,1 x ni1).
//         ph2 read {A mi2,3} + stage U2(kt+2)->P;               MFMA (mi2,3 x ni1).
//         ph3 stage U3(kt+2)->P; VM6;                           MFMA (mi2,3 x ni0).
// Waits (R12 derivation, load-order identical): pre-loop vmcnt(6)+BAR;
// steady one vmcnt(6) at ph3; tails kt30 vmcnt(0), kt31 none.
//
// 32x32x16 A/B lane layout: row(col) = l&31, k = ks*16 + (l>>5)*8 + 0..7.
// Read-side swizzle slot = ((ks<<1)|(l>>5)) ^ (l&7)  (16B units; row&7 == l&7
// for every base offset used - all are multiples of 8 rows).
// C/D layout (m74/m101): col = l&31, row = (reg&3) + 8*(reg>>2) + 4*(l>>5).

__device__ __forceinline__ void loadA2(bf16x8 (&a)[2][4], const __bf16* Sp,
                                       int base, int mb, const int (&ao)[4]) {
#pragma unroll
    for (int mi = 0; mi < 2; mi++)
#pragma unroll
        for (int ks = 0; ks < 4; ks++)
            a[mi][ks] = *(const bf16x8*)(Sp + base + (mb + mi) * 2048 + ao[ks]);
}
__device__ __forceinline__ void loadB1(bf16x8 (&b)[4], const __bf16* Sp,
                                       int base, int ni, const int (&ao)[4]) {
#pragma unroll
    for (int ks = 0; ks < 4; ks++)
        b[ks] = *(const bf16x8*)(Sp + base + ni * 4096 + ao[ks]);
}

template<int MB, int NI>
__device__ __forceinline__ void cluster8(f32x16 (&acc)[4][2], bf16x8 (&a)[2][4],
                                         bf16x8 (&b)[4]) {
    __builtin_amdgcn_s_setprio(1);
#pragma unroll
    for (int mi = 0; mi < 2; mi++)
#pragma unroll
        for (int ks = 0; ks < 4; ks++)
            acc[MB + mi][NI] = __builtin_amdgcn_mfma_f32_32x32x16_bf16(
                a[mi][ks], b[ks], acc[MB + mi][NI], 0, 0, 0);
    __builtin_amdgcn_s_setprio(0);
}

#define FENCE asm volatile("" ::: "memory")
#define BAR   do { FENCE; __builtin_amdgcn_s_barrier(); FENCE; } while (0)
#define BARO  do { BAR; asm volatile("s_waitcnt lgkmcnt(0)" ::: "memory"); \
                   __builtin_amdgcn_sched_barrier(0); } while (0)
#define VM6   asm volatile("s_waitcnt vmcnt(6)" ::: "memory")
#define VM0   asm volatile("s_waitcnt vmcnt(0)" ::: "memory")
#define VMX   do {} while (0)

#define STGA(P, kt, HF) do { \
    gload_lds16(pA + (size_t)((HF) * 64 + w * 8) * DM + (kt) * 64,       &As[P][((HF) * 8 + w) * 512]); \
    gload_lds16(pA + (size_t)((HF) * 64 + 128 + w * 8) * DM + (kt) * 64, &As[P][((HF) * 8 + 16 + w) * 512]); \
} while (0)
#define STGB(P, kt, HF) do { \
    gload_lds16(pB + (size_t)((HF) * 64 + w * 8) * DM + (kt) * 64,       &Bs[P][((HF) * 8 + w) * 512]); \
    gload_lds16(pB + (size_t)((HF) * 64 + 128 + w * 8) * DM + (kt) * 64, &Bs[P][((HF) * 8 + 16 + w) * 512]); \
} while (0)

#define KTILE(kt, P, Q, SG0, SG1, SG2, SG3, W3) do { \
    /* ph0: (mi0,1 x ni0) */ \
    loadA2(a, &As[P][0], baseA, 0, ao); \
    loadB1(b0, &Bs[P][0], baseB, 0, ao); \
    if (SG0) STGA(Q, (kt) + 1, 1);               /* U1(kt+1) */ \
    BARO; cluster8<0, 0>(acc, a, b0); BAR; \
    /* ph1: (mi0,1 x ni1) */ \
    loadB1(b1, &Bs[P][0], baseB, 1, ao); \
    if (SG1) STGA(P, (kt) + 2, 0);               /* U0(kt+2) */ \
    BARO; cluster8<0, 1>(acc, a, b1); BAR; \
    /* ph2: (mi2,3 x ni1) */ \
    loadA2(a, &As[P][0], baseA, 2, ao); \
    if (SG2) STGB(P, (kt) + 2, 0);               /* U2(kt+2) */ \
    BARO; cluster8<2, 1>(acc, a, b1); BAR; \
    /* ph3: (mi2,3 x ni0) */ \
    if (SG3) STGB(P, (kt) + 2, 1);               /* U3(kt+2) */ \
    W3; \
    BARO; cluster8<2, 0>(acc, a, b0); BAR; \
} while (0)

__global__ __launch_bounds__(512, 2)
void gemm_qkv(const __bf16* __restrict__ A,
              const __bf16* __restrict__ Wq,
              const __bf16* __restrict__ Wk,
              const __bf16* __restrict__ Wv,
              float* __restrict__ out) {
    __shared__ __bf16 As[2][16384];   // 2 x 256x64
    __shared__ __bf16 Bs[2][16384];

    int tid = threadIdx.x;
    int w = tid >> 6, l = tid & 63;
    int wm = w >> 2, wn = w & 3;

    // 2D-clustered XCD mapping (R6, verified)
    int bid = blockIdx.x;
    int x = bid & 7;
    int ridx = bid >> 3;               // 0..95
    int q = ridx >> 5;                 // round 0,1,2
    int s = ridx & 31;
    int mtp, ntp;
    if (q == 0)      { mtp = s >> 3;       ntp = s & 7; }
    else if (q == 1) { mtp = 4 + (s >> 3); ntp = s & 7; }
    else             { mtp = s & 7;        ntp = 8 + (s >> 3); }
    int mt = (x & 3) * 8 + mtp;        // 0..31
    int nt = (x >> 2) * 12 + ntp;      // 0..23
    int mat = nt >> 3, ntb = nt & 7;
    const __bf16* Wp = (mat == 0) ? Wq : (mat == 1) ? Wk : Wv;
    int row0 = mt * 256, colp = ntb * 256;

    // staging base pointers (rule 21: pre-swizzled source, linear LDS dest)
    int lr = l >> 3;
    int lco = ((l & 7) ^ lr) * 8;
    const __bf16* pA = A  + (size_t)(row0 + lr) * DM + lco;
    const __bf16* pB = Wp + (size_t)(colp + lr) * DM + lco;

    // ds_read lane constants for 32x32x16 frags (elements)
    int baseA = (wm * 128 + (l & 31)) * 64;
    int baseB = ((wn & 1) * 32 + (wn >> 1) * 128 + (l & 31)) * 64;
    int l5 = l >> 5;
    int ao[4];
#pragma unroll
    for (int ks = 0; ks < 4; ks++)
        ao[ks] = ((((ks << 1) | l5) ^ (l & 7)) * 8);

    // prologue: U0,U2,U3,U1(kt0)->buf0 [loads 1-8]; U0,U2,U3(kt1)->buf1 [9-14]
    STGA(0, 0, 0); STGB(0, 0, 0); STGB(0, 0, 1); STGA(0, 0, 1);
    STGA(1, 1, 0); STGB(1, 1, 0); STGB(1, 1, 1);

    f32x16 acc[4][2];
#pragma unroll
    for (int i = 0; i < 4; i++)
#pragma unroll
        for (int j = 0; j < 2; j++)
#pragma unroll
            for (int k = 0; k < 16; k++)
                acc[i][j][k] = 0.f;

    bf16x8 a[2][4], b0[4], b1[4];

    VM6;          // loads 1-8 = all of kt0 landed before first ds_read
    BAR;

#pragma unroll 1
    for (int kt = 0; kt < 30; kt += 2) {
        KTILE(kt,     0, 1, 1, 1, 1, 1, VM6);
        KTILE(kt + 1, 1, 0, 1, 1, 1, 1, VM6);
    }
    KTILE(30, 0, 1, 1, 0, 0, 0, VM0);   // stages only U1(31); drain
    KTILE(31, 1, 0, 0, 0, 0, 0, VMX);

    // ---------------- epilogue: head-split layout + fused RoPE ---------------
    // 32x32 C/D: col = l&31, row-in-frag = (reg&3) + 8*(reg>>2) + 4*(l>>5).
    // Thread col d = (wn&1)*32 + (l&31) (0..63); ni=0 -> d, ni=1 -> d+64:
    // the (d, d+64) rotation pair is (acc[mi][0][reg], acc[mi][1][reg]).
    float* op = out + (size_t)mat * MAT_ELEMS;
    int d = (wn & 1) * 32 + (l & 31);
    int head = ntb * 2 + (wn >> 1);
    int r_base = row0 + wm * 128 + 4 * l5;
    float iff = exp2f(-0.20762051f * (float)d);            // 10000^(-d/64)

    if (mat < 2) {
#pragma unroll
        for (int mi = 0; mi < 4; mi++) {
#pragma unroll
            for (int reg = 0; reg < 16; reg++) {
                int r = r_base + mi * 32 + (reg & 3) + 8 * (reg >> 2);
                int b2 = r >> 12, n = r & 4095;
                float* rowp = op + ((size_t)((b2 * NH + head) * NSEQ + n)) * HD;
                float lo = acc[mi][0][reg], hi = acc[mi][1][reg];
                float sv, cv;
                __sincosf((float)n * iff, &sv, &cv);
                rowp[d]      = lo * cv - hi * sv;
                rowp[d + 64] = hi * cv + lo * sv;
            }
        }
    } else {
#pragma unroll
        for (int mi = 0; mi < 4; mi++) {
#pragma unroll
            for (int reg = 0; reg < 16; reg++) {
                int r = r_base + mi * 32 + (reg & 3) + 8 * (reg >> 2);
                int b2 = r >> 12, n = r & 4095;
                float* rowp = op + ((size_t)((b2 * NH + head) * NSEQ + n)) * HD;
                rowp[d]      = acc[mi][0][reg];
                rowp[d + 64] = acc[mi][1][reg];
            }
        }
    }
}

// ---------------------------------------------------------------------------
extern "C" void kernel_launch(void* const* d_in, const int* in_sizes, int n_in,
                              void* d_out, int out_size, void* d_ws, size_t ws_size,
                              hipStream_t stream) {
    const float* x  = (const float*)d_in[0];
    const float* g  = (const float*)d_in[1];
    const float* be = (const float*)d_in[2];
    const float* wq = (const float*)d_in[3];
    const float* wk = (const float*)d_in[4];
    const float* wv = (const float*)d_in[5];
    float* out = (float*)d_out;

    char* ws = (char*)d_ws;
    __bf16* xnb = (__bf16*)ws;                                   // 32 MB
    __bf16* wb  = (__bf16*)(ws + 33554432);                      // 24 MB (q,k,v)

    lncvt_kernel<<<NROWS + 6144, 256, 0, stream>>>(x, g, be, wq, wk, wv, xnb, wb);
    gemm_qkv<<<768, 512, 0, stream>>>(xnb, wb, wb + 4194304, wb + 8388608, out);
}

// Round 15
// 228.315 us; speedup vs baseline: 1.0714x; 1.0714x over previous
//
#include <hip/hip_runtime.h>
#include <hip/hip_bf16.h>

// Fused LN -> QKV projection (bf16 MFMA, 256^2, 2-barrier-per-K-tile schedule:
// single unfenced read+MFMA window, stage behind closing barrier),
// 2D-clustered XCD mapping, RoPE fused into the GEMM epilogue.
// x:(2,4096,2048) f32; wq/wk/wv:(2048,2048) f32 row-major [e][d]; out: q,k,v
// each (2,16,4096,128) f32 concatenated.

typedef float f32x4 __attribute__((ext_vector_type(4)));
typedef __bf16 bf16x8 __attribute__((ext_vector_type(8)));
typedef __bf16 bf16x4 __attribute__((ext_vector_type(4)));

#define DM    2048
#define NSEQ  4096
#define NH    16
#define HD    128
#define NROWS 8192
#define MAT_ELEMS (2ull*NH*NSEQ*HD)

// ---------- async global->LDS (16B/lane, wave-uniform LDS base) --------------
typedef __attribute__((address_space(1))) const void GV;
typedef __attribute__((address_space(3))) void LV;
__device__ __forceinline__ void gload_lds16(const void* g, void* l) {
    __builtin_amdgcn_global_load_lds((GV*)g, (LV*)l, 16, 0, 0);
}

// ------------- LayerNorm + weight f32->bf16 cast, single launch --------------
__global__ __launch_bounds__(256)
void lncvt_kernel(const float* __restrict__ x, const float* __restrict__ g,
                  const float* __restrict__ be,
                  const float* __restrict__ wq, const float* __restrict__ wk,
                  const float* __restrict__ wv,
                  __bf16* __restrict__ xnb, __bf16* __restrict__ wb) {
    int bid = blockIdx.x;
    int tid = threadIdx.x;
    if (bid < NROWS) {
        int row = bid;
        const float4* xr = (const float4*)(x + (size_t)row * DM);
        float4 v0 = xr[tid];
        float4 v1 = xr[tid + 256];
        float s  = v0.x + v0.y + v0.z + v0.w + v1.x + v1.y + v1.z + v1.w;
        float ss = v0.x*v0.x + v0.y*v0.y + v0.z*v0.z + v0.w*v0.w
                 + v1.x*v1.x + v1.y*v1.y + v1.z*v1.z + v1.w*v1.w;
#pragma unroll
        for (int o = 32; o > 0; o >>= 1) {
            s  += __shfl_down(s, o);
            ss += __shfl_down(ss, o);
        }
        __shared__ float red[10];
        int wave = tid >> 6, lane = tid & 63;
        if (lane == 0) { red[wave] = s; red[4 + wave] = ss; }
        __syncthreads();
        if (tid == 0) {
            float S  = red[0] + red[1] + red[2] + red[3];
            float SS = red[4] + red[5] + red[6] + red[7];
            float mu  = S * (1.0f / DM);
            float var = SS * (1.0f / DM) - mu * mu;
            red[8] = mu;
            red[9] = rsqrtf(var + 1e-5f);
        }
        __syncthreads();
        float mu = red[8], rs = red[9];

        const float4* gp = (const float4*)g;
        const float4* bp = (const float4*)be;
        bf16x4* orow = (bf16x4*)(xnb + (size_t)row * DM);
        {
            float4 g0 = gp[tid], b0 = bp[tid];
            bf16x4 o;
            o[0] = (__bf16)((v0.x - mu) * rs * g0.x + b0.x);
            o[1] = (__bf16)((v0.y - mu) * rs * g0.y + b0.y);
            o[2] = (__bf16)((v0.z - mu) * rs * g0.z + b0.z);
            o[3] = (__bf16)((v0.w - mu) * rs * g0.w + b0.w);
            orow[tid] = o;
        }
        {
            float4 g1 = gp[tid + 256], b1 = bp[tid + 256];
            bf16x4 o;
            o[0] = (__bf16)((v1.x - mu) * rs * g1.x + b1.x);
            o[1] = (__bf16)((v1.y - mu) * rs * g1.y + b1.y);
            o[2] = (__bf16)((v1.z - mu) * rs * g1.z + b1.z);
            o[3] = (__bf16)((v1.w - mu) * rs * g1.w + b1.w);
            orow[tid + 256] = o;
        }
    } else {
        int cb = bid - NROWS;                   // 0..6143
        const float* a = (cb < 2048) ? wq : (cb < 4096) ? wk : wv;
        size_t base = ((size_t)(cb & 2047) * 256 + tid) * 8;
        float4 v0 = *(const float4*)(a + base);
        float4 v1 = *(const float4*)(a + base + 4);
        bf16x8 r;
        r[0] = (__bf16)v0.x; r[1] = (__bf16)v0.y; r[2] = (__bf16)v0.z; r[3] = (__bf16)v0.w;
        r[4] = (__bf16)v1.x; r[5] = (__bf16)v1.y; r[6] = (__bf16)v1.z; r[7] = (__bf16)v1.w;
        *(bf16x8*)(wb + (size_t)(cb >> 11) * 4194304 + base) = r;
    }
}

// =========  256x256 QKV GEMM, 2 barriers + 1 vmcnt per K-tile  ===============
// Tile 256x256, BK=64, 8 waves (2Mx4N), LDS 128KiB dbuf, XOR-swizzle
// (R12 addressing, 0 conflicts measured).
// Body(kt), P = buf kt&1:
//   vmcnt(8)  [kt's 8 units landed; outstanding = kt+1's 8, staged body(kt-1)]
//   BAR       [cross-wave visibility of kt's data]
//   24 ds_read + 64 MFMA, UNFENCED  [compiler fine-grained lgkm -> early MFMAs
//             overlap late reads within the wave; port serves skewed waves]
//   BAR       [every wave's reads of P complete (in-order lgkm: reads precede
//             the MFMAs that precede this barrier) -> staging P is race-free]
//   stage all 4 units of kt+2 -> P  [8 gloads]
// Waits: kt0..30 vmcnt(8) (prologue = 16 loads, kt0 needs oldest 8);
// kt31 vmcnt(0) (kt30 stages nothing -> kt31's units are newest 8).

__device__ __forceinline__ void loadA4(bf16x8 (&a)[4][2], const __bf16* Sp,
                                       int base, int mb, int o0) {
#pragma unroll
    for (int mi = 0; mi < 4; mi++)
#pragma unroll
        for (int ks = 0; ks < 2; ks++)
            a[mi][ks] = *(const bf16x8*)(Sp + base + (mb + mi) * 1024 + (o0 ^ (ks * 32)));
}
// fragments f=0,1 at B rows base + f*16 + (cb>>1)*64
__device__ __forceinline__ void loadB2(bf16x8 (&b)[2][2], const __bf16* Sp,
                                       int base, int cb, int o0) {
#pragma unroll
    for (int f = 0; f < 2; f++)
#pragma unroll
        for (int ks = 0; ks < 2; ks++)
            b[f][ks] = *(const bf16x8*)(Sp + base + (f * 16 + (cb >> 1) * 64) * 64 + (o0 ^ (ks * 32)));
}

template<int RB, int CB>
__device__ __forceinline__ void cluster(f32x4 (&acc)[8][4], bf16x8 (&a)[4][2],
                                        bf16x8 (&b)[2][2]) {
    __builtin_amdgcn_s_setprio(1);
#pragma unroll
    for (int mi = 0; mi < 4; mi++)
#pragma unroll
        for (int ni = 0; ni < 2; ni++)
#pragma unroll
            for (int ks = 0; ks < 2; ks++)
                acc[RB + mi][CB + ni] = __builtin_amdgcn_mfma_f32_16x16x32_bf16(
                    a[mi][ks], b[ni][ks], acc[RB + mi][CB + ni], 0, 0, 0);
    __builtin_amdgcn_s_setprio(0);
}

#define FENCE asm volatile("" ::: "memory")
#define BAR   do { FENCE; __builtin_amdgcn_s_barrier(); FENCE; } while (0)
#define VM8   asm volatile("s_waitcnt vmcnt(8)" ::: "memory")
#define VM0   asm volatile("s_waitcnt vmcnt(0)" ::: "memory")

// stage A/B half HF (0: rows {0-63,128-191}; 1: rows {64-127,192-255}) of
// K-tile kt into buf P.  Per-wave: rowgroups {HF*8+w, HF*8+16+w}.
#define STGA(P, kt, HF) do { \
    gload_lds16(pA + (size_t)((HF) * 64 + w * 8) * DM + (kt) * 64,       &As[P][((HF) * 8 + w) * 512]); \
    gload_lds16(pA + (size_t)((HF) * 64 + 128 + w * 8) * DM + (kt) * 64, &As[P][((HF) * 8 + 16 + w) * 512]); \
} while (0)
#define STGB(P, kt, HF) do { \
    gload_lds16(pB + (size_t)((HF) * 64 + w * 8) * DM + (kt) * 64,       &Bs[P][((HF) * 8 + w) * 512]); \
    gload_lds16(pB + (size_t)((HF) * 64 + 128 + w * 8) * DM + (kt) * 64, &Bs[P][((HF) * 8 + 16 + w) * 512]); \
} while (0)

#define KTILE(kt, P, SG, W) do { \
    W; BAR; \
    loadA4(a,  &As[P][0], baseA, 0, o0); \
    loadB2(b0, &Bs[P][0], baseB, 0, o0); \
    loadB2(b1, &Bs[P][0], baseB, 2, o0); \
    cluster<0, 0>(acc, a, b0); \
    cluster<0, 2>(acc, a, b1); \
    loadA4(a, &As[P][0], baseA, 4, o0); \
    cluster<4, 0>(acc, a, b0); \
    cluster<4, 2>(acc, a, b1); \
    BAR; \
    if (SG) { STGA(P, (kt) + 2, 0); STGA(P, (kt) + 2, 1); \
              STGB(P, (kt) + 2, 0); STGB(P, (kt) + 2, 1); } \
} while (0)

__global__ __launch_bounds__(512, 2)
void gemm_qkv(const __bf16* __restrict__ A,
              const __bf16* __restrict__ Wq,
              const __bf16* __restrict__ Wk,
              const __bf16* __restrict__ Wv,
              float* __restrict__ out) {
    __shared__ __bf16 As[2][16384];   // 2 x 256x64
    __shared__ __bf16 Bs[2][16384];

    int tid = threadIdx.x;
    int w = tid >> 6, l = tid & 63;
    int wm = w >> 2, wn = w & 3;

    // 2D-clustered XCD mapping (R6, verified)
    int bid = blockIdx.x;
    int x = bid & 7;
    int ridx = bid >> 3;               // 0..95
    int q = ridx >> 5;                 // round 0,1,2
    int s = ridx & 31;
    int mtp, ntp;
    if (q == 0)      { mtp = s >> 3;       ntp = s & 7; }
    else if (q == 1) { mtp = 4 + (s >> 3); ntp = s & 7; }
    else             { mtp = s & 7;        ntp = 8 + (s >> 3); }
    int mt = (x & 3) * 8 + mtp;        // 0..31
    int nt = (x >> 2) * 12 + ntp;      // 0..23
    int mat = nt >> 3, ntb = nt & 7;
    const __bf16* Wp = (mat == 0) ? Wq : (mat == 1) ? Wk : Wv;
    int row0 = mt * 256, colp = ntb * 256;

    // staging base pointers (rule 21: pre-swizzled source, linear LDS dest)
    int lr = l >> 3;
    int lco = ((l & 7) ^ lr) * 8;
    const __bf16* pA = A  + (size_t)(row0 + lr) * DM + lco;
    const __bf16* pB = Wp + (size_t)(colp + lr) * DM + lco;

    // ds_read lane constants (elements); read-side XOR matches write swizzle
    int baseA = (wm * 128 + (l & 15)) * 64;
    int baseB = ((wn & 1) * 32 + (wn >> 1) * 128 + (l & 15)) * 64;
    int o0 = ((l >> 4) * 8) ^ ((l & 7) * 8);

    // prologue: kt0 -> buf0 [loads 1-8]; kt1 -> buf1 [loads 9-16]
    STGA(0, 0, 0); STGA(0, 0, 1); STGB(0, 0, 0); STGB(0, 0, 1);
    STGA(1, 1, 0); STGA(1, 1, 1); STGB(1, 1, 0); STGB(1, 1, 1);

    f32x4 acc[8][4];
#pragma unroll
    for (int i = 0; i < 8; i++)
#pragma unroll
        for (int j = 0; j < 4; j++)
            acc[i][j] = (f32x4){0.f, 0.f, 0.f, 0.f};

    bf16x8 a[4][2], b0[2][2], b1[2][2];

#pragma unroll 1
    for (int kt = 0; kt < 30; kt += 2) {
        KTILE(kt,     0, 1, VM8);
        KTILE(kt + 1, 1, 1, VM8);
    }
    KTILE(30, 0, 0, VM8);
    KTILE(31, 1, 0, VM0);

    // ---------------- epilogue: head-split layout + fused RoPE ---------------
    // acc[mi][ni] col = (wn&1)*32 + (ni&1)*16 + (wn>>1)*128 + (ni>>1)*64 + (l&15)
    // -> (acc[mi][ni], acc[mi][ni+2]) is the (d, d+64) rotation pair, ni=0,1.
    float* op = out + (size_t)mat * MAT_ELEMS;
    int hd_lo = (wn & 1) * 32 + (l & 15);                 // d for ni=0 (0..63)
    int head = ntb * 2 + (wn >> 1);
    int r_base = row0 + wm * 128 + ((l >> 4) << 2);
    float if0 = exp2f(-0.20762051f * (float)hd_lo);        // 10000^(-d/64)
    float if1 = exp2f(-0.20762051f * (float)(hd_lo + 16));

    if (mat < 2) {
#pragma unroll
        for (int mi = 0; mi < 8; mi++) {
#pragma unroll
            for (int j = 0; j < 4; j++) {
                int r = r_base + mi * 16 + j;
                int b = r >> 12, n = r & 4095;
                float fn = (float)n;
                float* rowp = op + ((size_t)((b * NH + head) * NSEQ + n)) * HD;
#pragma unroll
                for (int ni = 0; ni < 2; ni++) {
                    float lo = acc[mi][ni][j], hi = acc[mi][ni + 2][j];
                    float sv, cv;
                    __sincosf(fn * (ni ? if1 : if0), &sv, &cv);
                    rowp[hd_lo + ni * 16]      = lo * cv - hi * sv;
                    rowp[hd_lo + ni * 16 + 64] = hi * cv + lo * sv;
                }
            }
        }
    } else {
#pragma unroll
        for (int mi = 0; mi < 8; mi++) {
#pragma unroll
            for (int j = 0; j < 4; j++) {
                int r = r_base + mi * 16 + j;
                int b = r >> 12, n = r & 4095;
                float* rowp = op + ((size_t)((b * NH + head) * NSEQ + n)) * HD;
#pragma unroll
                for (int ni = 0; ni < 2; ni++) {
                    rowp[hd_lo + ni * 16]      = acc[mi][ni][j];
                    rowp[hd_lo + ni * 16 + 64] = acc[mi][ni + 2][j];
                }
            }
        }
    }
}

// ---------------------------------------------------------------------------
extern "C" void kernel_launch(void* const* d_in, const int* in_sizes, int n_in,
                              void* d_out, int out_size, void* d_ws, size_t ws_size,
                              hipStream_t stream) {
    const float* x  = (const float*)d_in[0];
    const float* g  = (const float*)d_in[1];
    const float* be = (const float*)d_in[2];
    const float* wq = (const float*)d_in[3];
    const float* wk = (const float*)d_in[4];
    const float* wv = (const float*)d_in[5];
    float* out = (float*)d_out;

    char* ws = (char*)d_ws;
    __bf16* xnb = (__bf16*)ws;                                   // 32 MB
    __bf16* wb  = (__bf16*)(ws + 33554432);                      // 24 MB (q,k,v)

    lncvt_kernel<<<NROWS + 6144, 256, 0, stream>>>(x, g, be, wq, wk, wv, xnb, wb);
    gemm_qkv<<<768, 512, 0, stream>>>(xnb, wb, wb + 4194304, wb + 8388608, out);
}